// Round 7
// baseline (177.114 us; speedup 1.0000x reference)
//
#include <hip/hip_runtime.h>
#include <hip/hip_bf16.h>

#define B_N 4096
#define L_K 128
#define NPART 4096   // one partial per wave-task

typedef __bf16 bf16x8 __attribute__((ext_vector_type(8)));
typedef float  f32x4  __attribute__((ext_vector_type(4)));

// ---------------------------------------------------------------------------
// prep: labels f32 -> bf16 (ws), and inv[i] = 1/sqrt(||labels_i||^2 + 128)
// ---------------------------------------------------------------------------
__global__ __launch_bounds__(256) void prep_kernel(const float* __restrict__ labels,
                                                   unsigned short* __restrict__ lb,
                                                   float* __restrict__ inv) {
    const int wave = blockIdx.x * 4 + (threadIdx.x >> 6);
    const int lane = threadIdx.x & 63;
    const int row  = wave;

    const float x0 = labels[row * L_K + lane];
    const float x1 = labels[row * L_K + 64 + lane];

    __hip_bfloat16 h0 = __float2bfloat16(x0);
    __hip_bfloat16 h1 = __float2bfloat16(x1);
    lb[row * L_K + lane]      = *reinterpret_cast<unsigned short*>(&h0);
    lb[row * L_K + 64 + lane] = *reinterpret_cast<unsigned short*>(&h1);

    float s = x0 * x0 + x1 * x1;
    #pragma unroll
    for (int m = 32; m >= 1; m >>= 1) s += __shfl_xor(s, m);
    if (lane == 0) inv[row] = 1.0f / sqrtf(s + 128.0f);
}

// ---------------------------------------------------------------------------
// main: NO LDS, NO barriers.
// Each wave = one task: 16-row strip x 256 cols (4 col-tiles of 64).
// Per tile: gram via 16 MFMA (lb L2-resident), m = floor(cos) kept IN REGS
// (C/D layout: col = lane&15, row = (lane>>4)*4 + reg), then each lane loads
// o0/o1 at exactly its fragment's (row,col) positions and accumulates
// smooth-L1 via loss = 0.5*min(d,1)^2 + max(d,1) - 1.
// Round-6 lesson: the "-1 per element" constant (8192/wave) must be
// subtracted ONCE per wave AFTER the lane reduction, not once per lane
// (that bug produced absmax 62.92 == 8192*63/8192 arithmetic exactly).
// ---------------------------------------------------------------------------
__global__ __launch_bounds__(256) void main_kernel(const float* __restrict__ o0,
                                                   const float* __restrict__ o1,
                                                   const unsigned short* __restrict__ lb,
                                                   const float* __restrict__ inv,
                                                   float* __restrict__ partials) {
    const int w = threadIdx.x >> 6;
    const int l = threadIdx.x & 63;
    const int task = blockIdx.x * 4 + w;     // 0..4095
    const int s = task >> 4;                 // row strip 0..255
    const int q = task & 15;                 // col quad  0..15

    const int fr = l & 15;                   // fragment row/col index
    const int fk = (l >> 4) * 8;             // k sub-offset
    const int r0 = s * 16;                   // strip row base
    const int rr = (l >> 4) * 4;             // lane row sub-base (C/D layout)

    // A fragments + row-inv: strip-constant, hoisted
    bf16x8 a[4];
    #pragma unroll
    for (int kk = 0; kk < 4; ++kk)
        a[kk] = *reinterpret_cast<const bf16x8*>(
            lb + (size_t)(r0 + fr) * L_K + kk * 32 + fk);

    float invi[4];
    #pragma unroll
    for (int r = 0; r < 4; ++r) invi[r] = inv[r0 + rr + r];

    float sumA = 0.0f, sumB = 0.0f;

    #pragma unroll
    for (int t = 0; t < 4; ++t) {
        const int c0 = q * 256 + t * 64;

        // B loads (L2) + MFMA — issued before the HBM o-burst so the
        // in-order vmcnt doesn't make MFMA wait on HBM.
        f32x4 acc[4] = {};
        #pragma unroll
        for (int kk = 0; kk < 4; ++kk) {
            #pragma unroll
            for (int ct = 0; ct < 4; ++ct) {
                const bf16x8 b = *reinterpret_cast<const bf16x8*>(
                    lb + (size_t)(c0 + ct * 16 + fr) * L_K + kk * 32 + fk);
                acc[ct] = __builtin_amdgcn_mfma_f32_16x16x32_bf16(a[kk], b, acc[ct], 0, 0, 0);
            }
        }

        // o-burst: 32 scalar loads at this lane's fragment positions
        float p0v[16], p1v[16];
        #pragma unroll
        for (int r = 0; r < 4; ++r) {
            const size_t rowoff = (size_t)(r0 + rr + r) * B_N + (size_t)(c0 + fr);
            #pragma unroll
            for (int ct = 0; ct < 4; ++ct) {
                p0v[r * 4 + ct] = o0[rowoff + ct * 16];
                p1v[r * 4 + ct] = o1[rowoff + ct * 16];
            }
        }

        float invj[4];
        #pragma unroll
        for (int ct = 0; ct < 4; ++ct) invj[ct] = inv[c0 + ct * 16 + fr];

        // consume: m in regs, smooth-L1 via min/max identity
        #pragma unroll
        for (int ct = 0; ct < 4; ++ct) {
            #pragma unroll
            for (int r = 0; r < 4; ++r) {
                const float m  = floorf((acc[ct][r] + 128.0f) * invi[r] * invj[ct]);
                const float d0 = fabsf(p0v[r * 4 + ct] - m);
                const float d1 = fabsf(p1v[r * 4 + ct] - m);
                const float u0 = fminf(d0, 1.0f), v0 = fmaxf(d0, 1.0f);
                const float u1 = fminf(d1, 1.0f), v1 = fmaxf(d1, 1.0f);
                sumA = fmaf(u0, u0, sumA);
                sumA = fmaf(u1, u1, sumA);
                sumB += v0 + v1;
            }
        }
    }

    // lane partial (no constant here!), reduce across 64 lanes first
    float lsum = 0.5f * sumA + sumB;
    #pragma unroll
    for (int m = 32; m >= 1; m >>= 1) lsum += __shfl_xor(lsum, m);
    // per-wave: 16 rows x 256 cols x 2 matrices = 8192 elements, "-1" each,
    // folded out ONCE per wave after the reduction
    if (l == 0) partials[task] = lsum - 8192.0f;
}

// ---------------------------------------------------------------------------
// finalize: one block, reduce 4096 partials in double, scale
// ---------------------------------------------------------------------------
__global__ __launch_bounds__(1024) void fin_kernel(const float* __restrict__ partials,
                                                   float* __restrict__ out) {
    __shared__ double wred[16];
    double s = 0.0;
    for (int i = threadIdx.x; i < NPART; i += 1024) s += (double)partials[i];
    #pragma unroll
    for (int m = 32; m >= 1; m >>= 1) s += __shfl_xor(s, m);
    const int l = threadIdx.x & 63, w = threadIdx.x >> 6;
    if (l == 0) wred[w] = s;
    __syncthreads();
    if (threadIdx.x == 0) {
        double t = 0.0;
        #pragma unroll
        for (int i = 0; i < 16; ++i) t += wred[i];
        out[0] = (float)(t / (2.0 * (double)B_N * (double)B_N));
    }
}

extern "C" void kernel_launch(void* const* d_in, const int* in_sizes, int n_in,
                              void* d_out, int out_size, void* d_ws, size_t ws_size,
                              hipStream_t stream) {
    const float* o0     = (const float*)d_in[0];
    const float* o1     = (const float*)d_in[1];
    const float* labels = (const float*)d_in[2];
    float* out = (float*)d_out;

    char* ws = (char*)d_ws;
    unsigned short* lb = (unsigned short*)ws;                         // 1 MB bf16 labels
    float* inv      = (float*)(ws + (size_t)B_N * L_K * 2);           // 16 KB
    float* partials = (float*)(ws + (size_t)B_N * L_K * 2 + B_N * 4); // 16 KB

    prep_kernel<<<B_N / 4, 256, 0, stream>>>(labels, lb, inv);
    main_kernel<<<NPART / 4, 256, 0, stream>>>(o0, o1, lb, inv, partials);
    fin_kernel<<<1, 1024, 0, stream>>>(partials, out);
}

// Round 8
// 169.938 us; speedup vs baseline: 1.0422x; 1.0422x over previous
//
#include <hip/hip_runtime.h>
#include <hip/hip_bf16.h>

#define B_N 4096
#define L_K 128
#define NPART 16384   // one partial per wave-task (256 strips x 64 col-tiles)

typedef __bf16 bf16x8 __attribute__((ext_vector_type(8)));
typedef float  f32x4  __attribute__((ext_vector_type(4)));

// ---------------------------------------------------------------------------
// prep: labels f32 -> bf16 (ws), and inv[i] = 1/sqrt(||labels_i||^2 + 128)
// ---------------------------------------------------------------------------
__global__ __launch_bounds__(256) void prep_kernel(const float* __restrict__ labels,
                                                   unsigned short* __restrict__ lb,
                                                   float* __restrict__ inv) {
    const int wave = blockIdx.x * 4 + (threadIdx.x >> 6);
    const int lane = threadIdx.x & 63;
    const int row  = wave;

    const float x0 = labels[row * L_K + lane];
    const float x1 = labels[row * L_K + 64 + lane];

    __hip_bfloat16 h0 = __float2bfloat16(x0);
    __hip_bfloat16 h1 = __float2bfloat16(x1);
    lb[row * L_K + lane]      = *reinterpret_cast<unsigned short*>(&h0);
    lb[row * L_K + 64 + lane] = *reinterpret_cast<unsigned short*>(&h1);

    float s = x0 * x0 + x1 * x1;
    #pragma unroll
    for (int m = 32; m >= 1; m >>= 1) s += __shfl_xor(s, m);
    if (lane == 0) inv[row] = 1.0f / sqrtf(s + 128.0f);
}

// ---------------------------------------------------------------------------
// main (round 8): one wave = one 16x64 tile; 16384 tasks / 4096 blocks.
// No cross-wave sync. Per task:
//   1. issue 8 x dwordx4 o-loads (1KB/instr, fully coalesced) -> in flight
//      under everything below
//   2. gram: 16 x mfma_f32_16x16x32_bf16 (lb L2-resident)
//   3. m = floor(cos) -> wave-private LDS transpose (stride 68: 2-way write
//      conflicts = free; 272B row pitch = 17x16B so b128 reads stay aligned);
//      same-wave DS ops are in-order -> NO barrier
//   4. read m back in streaming layout (b128), consume against o regs
// Round-7 lessons: 1024-block grid starved turnover (occ 23%) and 4B scalar
// o-loads (256B/instr) cut MLP -> 67us. Round-4 lesson: barrier vmcnt(0)
// drains are the other failure mode. This structure has neither.
// Round-6 lesson: "-1 per element" constant subtracted ONCE per wave, after
// the lane reduction (2048 elems/wave here).
// ---------------------------------------------------------------------------
__global__ __launch_bounds__(256) void main_kernel(const float* __restrict__ o0,
                                                   const float* __restrict__ o1,
                                                   const unsigned short* __restrict__ lb,
                                                   const float* __restrict__ inv,
                                                   float* __restrict__ partials) {
    __shared__ __align__(16) float m_lds[4][16][68];   // 17.4 KB/block

    const int w = threadIdx.x >> 6;
    const int l = threadIdx.x & 63;
    const int task = blockIdx.x * 4 + w;     // 0..16383
    const int s = task >> 6;                 // row strip 0..255
    const int c = task & 63;                 // col tile  0..63

    const int fr = l & 15;                   // fragment row/col index
    const int fk = (l >> 4) * 8;             // k sub-offset
    const int g  = l >> 4;                   // lane group 0..3
    const int rr = g * 4;                    // C/D lane row sub-base
    const int r0 = s * 16;
    const int c0 = c * 64;

    // ---- 1. o-loads first: 8 x 1KB, stay in flight under MFMA+LDS phase ----
    f32x4 p0[4], p1[4];
    #pragma unroll
    for (int v = 0; v < 4; ++v) {
        const size_t goff = (size_t)(r0 + 4 * v + g) * B_N + (size_t)(c0 + fr * 4);
        p0[v] = *reinterpret_cast<const f32x4*>(o0 + goff);
        p1[v] = *reinterpret_cast<const f32x4*>(o1 + goff);
    }

    // ---- 2. gram via MFMA (lb is L2-resident) ----
    bf16x8 a[4];
    #pragma unroll
    for (int kk = 0; kk < 4; ++kk)
        a[kk] = *reinterpret_cast<const bf16x8*>(
            lb + (size_t)(r0 + fr) * L_K + kk * 32 + fk);

    f32x4 acc[4] = {};
    #pragma unroll
    for (int kk = 0; kk < 4; ++kk) {
        #pragma unroll
        for (int ct = 0; ct < 4; ++ct) {
            const bf16x8 b = *reinterpret_cast<const bf16x8*>(
                lb + (size_t)(c0 + ct * 16 + fr) * L_K + kk * 32 + fk);
            acc[ct] = __builtin_amdgcn_mfma_f32_16x16x32_bf16(a[kk], b, acc[ct], 0, 0, 0);
        }
    }

    float invi[4];
    #pragma unroll
    for (int r = 0; r < 4; ++r) invi[r] = inv[r0 + rr + r];
    float invj[4];
    #pragma unroll
    for (int ct = 0; ct < 4; ++ct) invj[ct] = inv[c0 + ct * 16 + fr];

    // ---- 3. m -> LDS (C/D layout: col = lane&15 (+16ct), row = rr + reg) ----
    #pragma unroll
    for (int ct = 0; ct < 4; ++ct) {
        #pragma unroll
        for (int r = 0; r < 4; ++r) {
            m_lds[w][rr + r][ct * 16 + fr] =
                floorf((acc[ct][r] + 128.0f) * invi[r] * invj[ct]);
        }
    }

    // ---- 4. streaming read-back + smooth-L1 (0.5*min(d,1)^2 + max(d,1) - 1) ----
    float sumA = 0.0f, sumB = 0.0f;
    #pragma unroll
    for (int v = 0; v < 4; ++v) {
        const f32x4 mm = *reinterpret_cast<const f32x4*>(&m_lds[w][4 * v + g][fr * 4]);
        #pragma unroll
        for (int q = 0; q < 4; ++q) {
            const float d0 = fabsf(p0[v][q] - mm[q]);
            const float d1 = fabsf(p1[v][q] - mm[q]);
            const float u0 = fminf(d0, 1.0f), v0 = fmaxf(d0, 1.0f);
            const float u1 = fminf(d1, 1.0f), v1 = fmaxf(d1, 1.0f);
            sumA = fmaf(u0, u0, sumA);
            sumA = fmaf(u1, u1, sumA);
            sumB += v0 + v1;
        }
    }

    // lane partial (no constant here), reduce across 64 lanes first
    float lsum = 0.5f * sumA + sumB;
    #pragma unroll
    for (int m = 32; m >= 1; m >>= 1) lsum += __shfl_xor(lsum, m);
    // per-wave: 16 x 64 x 2 = 2048 elements, "-1" each, folded once per wave
    if (l == 0) partials[task] = lsum - 2048.0f;
}

// ---------------------------------------------------------------------------
// finalize: one block, reduce 16384 partials in double, scale
// ---------------------------------------------------------------------------
__global__ __launch_bounds__(1024) void fin_kernel(const float* __restrict__ partials,
                                                   float* __restrict__ out) {
    __shared__ double wred[16];
    double s = 0.0;
    for (int i = threadIdx.x; i < NPART; i += 1024) s += (double)partials[i];
    #pragma unroll
    for (int m = 32; m >= 1; m >>= 1) s += __shfl_xor(s, m);
    const int l = threadIdx.x & 63, w = threadIdx.x >> 6;
    if (l == 0) wred[w] = s;
    __syncthreads();
    if (threadIdx.x == 0) {
        double t = 0.0;
        #pragma unroll
        for (int i = 0; i < 16; ++i) t += wred[i];
        out[0] = (float)(t / (2.0 * (double)B_N * (double)B_N));
    }
}

extern "C" void kernel_launch(void* const* d_in, const int* in_sizes, int n_in,
                              void* d_out, int out_size, void* d_ws, size_t ws_size,
                              hipStream_t stream) {
    const float* o0     = (const float*)d_in[0];
    const float* o1     = (const float*)d_in[1];
    const float* labels = (const float*)d_in[2];
    float* out = (float*)d_out;

    char* ws = (char*)d_ws;
    unsigned short* lb = (unsigned short*)ws;                         // 1 MB bf16 labels
    float* inv      = (float*)(ws + (size_t)B_N * L_K * 2);           // 16 KB
    float* partials = (float*)(ws + (size_t)B_N * L_K * 2 + B_N * 4); // 64 KB

    prep_kernel<<<B_N / 4, 256, 0, stream>>>(labels, lb, inv);
    main_kernel<<<NPART / 4, 256, 0, stream>>>(o0, o1, lb, inv, partials);
    fin_kernel<<<1, 1024, 0, stream>>>(partials, out);
}